// Round 13
// baseline (31.799 us; speedup 1.0000x reference)
//
#include <hip/hip_runtime.h>
#include <math.h>

namespace {

constexpr int IMG  = 128;
constexpr int NPIX = IMG * IMG;
constexpr int B    = 4;
constexpr int V    = 600;
constexpr int F    = 1000;
constexpr float FOCALF = 1.5f;
constexpr float EPSF   = 1e-8f;
constexpr float SLACK  = 1e-5f;    // >> max rounding error of w (~3e-6)
// rcp-filter: |z~ - z| <= ~1e-5 when |den| >= DENSAFE (sum(s_i)=1 +- 3e-3,
// z in [1,3], all terms same-sign). ZEPS = 1e-4 gives >=10x margin.
// |den| < DENSAFE faces always take the exact path.
constexpr float ZEPS    = 1e-4f;
constexpr float DENSAFE = 1e-3f;

__device__ inline float seg_dist2(float px, float py, float ax, float ay,
                                  float bx, float by) {
#pragma clang fp contract(off)
    float ex = bx - ax, ey = by - ay;
    float dx = px - ax, dy = py - ay;
    float ee = fmaxf(ex * ex + ey * ey, EPSF);
    float t  = (dx * ex + dy * ey) / ee;
    t = fminf(fmaxf(t, 0.0f), 1.0f);
    float rx = dx - t * ex;
    float ry = dy - t * ey;
    return rx * rx + ry * ry;
}

// facedata layout [b][f][20] (5 x float4, 80B):
//  0:e0x 1:e0y 2:bx 3:by | 4:e1x 5:e1y 6:cx 7:cy | 8:e2x 9:e2y 10:ax 11:ay |
// 12:den 13:azr 14:bzr 15:czr | 16:az 17:bz 18:cz 19:pad
// azr = az*rcp(den) etc. (filter-only values; exact path uses az,bz,cz).
// den==0 marks degenerate/culled. Also clears zbest — fused to save a launch.
__global__ __launch_bounds__(256) void setup_clear(const float* __restrict__ verts,
                                                   const int* __restrict__ faces,
                                                   float* __restrict__ fdata,
                                                   unsigned long long* __restrict__ zbest) {
#pragma clang fp contract(off)
    int t = blockIdx.x * 256 + threadIdx.x;   // grid covers B*NPIX = 65536
    zbest[t] = ~0ULL;
    if (t >= B * F) return;
    int b = t / F, f = t - b * F;
    int i0 = faces[f * 3 + 0], i1 = faces[f * 3 + 1], i2 = faces[f * 3 + 2];
    const float* vb = verts + (size_t)b * V * 3;
    float x0 = vb[i0 * 3], y0 = vb[i0 * 3 + 1], z0 = vb[i0 * 3 + 2];
    float x1 = vb[i1 * 3], y1 = vb[i1 * 3 + 1], z1 = vb[i1 * 3 + 2];
    float x2 = vb[i2 * 3], y2 = vb[i2 * 3 + 1], z2 = vb[i2 * 3 + 2];
    // exact reference projection
    float ax = (FOCALF * x0) / z0, ay = (FOCALF * y0) / z0;
    float bx = (FOCALF * x1) / z1, by = (FOCALF * y1) / z1;
    float cx = (FOCALF * x2) / z2, cy = (FOCALF * y2) / z2;
    // edge vectors (identical rounding to reference's inline subtractions)
    float e0x = cx - bx, e0y = cy - by;   // edge for w0 (v1->v2), base b
    float e1x = ax - cx, e1y = ay - cy;   // edge for w1 (v2->v0), base c
    float e2x = bx - ax, e2y = by - ay;   // edge for w2 (v0->v1), base a
    float den = e2x * (cy - ay) - e2y * (cx - ax);   // == reference area tree
    if (!(fabsf(den) > EPSF)) den = 0.0f;
    const float rd = __builtin_amdgcn_rcpf(den);     // filter-only
    float* o = fdata + (size_t)t * 20;
    o[0]  = e0x;  o[1]  = e0y;  o[2]  = bx;       o[3]  = by;
    o[4]  = e1x;  o[5]  = e1y;  o[6]  = cx;       o[7]  = cy;
    o[8]  = e2x;  o[9]  = e2y;  o[10] = ax;       o[11] = ay;
    o[12] = den;  o[13] = z0 * rd; o[14] = z1 * rd; o[15] = z2 * rd;
    o[16] = z0;   o[17] = z1;   o[18] = z2;       o[19] = 0.0f;
}

// Fused bin+shade. 1024 blocks x 512 thr (8 waves). Block = (ch, b, slice):
// one 64-face chunk x 16 tiles (4x4 lattice). Faces register-pinned for the
// bin test AND staged once to LDS; survivor loop broadcasts via ds_read_b128
// at wave-uniform addresses. Cheap path: w's + sign tests + precomputed-rcp
// z~ window (provably-safe skips only); bit-exact IEEE path only when some
// lane might improve its bound.
__global__ __launch_bounds__(512, 8) void rast(const float* __restrict__ fdata,
                                               unsigned long long* __restrict__ zbest) {
#pragma clang fp contract(off)
    __shared__ float4 sface[64 * 5];     // 5 KB: this block's chunk
    __shared__ unsigned int lticket;
    const int tid  = threadIdx.x;
    const int lane = tid & 63;
    const int bk   = blockIdx.x;
    const int ch   = bk & 15;          // face chunk
    const int b    = (bk >> 4) & 3;    // image
    const int slice = bk >> 6;         // 0..15 -> 4x4 lattice phase
    if (tid == 0) lticket = 0u;

    // pin this chunk's face data: one face per lane, lives in VGPRs
    const int f0 = ch * 64;
    const int sz = min(64, F - f0);    // 64, last chunk 40
    const int fl = min(f0 + lane, F - 1);
    const float4* fd4 = (const float4*)(fdata + ((size_t)b * F + fl) * 20);
    const float4 q0 = fd4[0], q1 = fd4[1], q2 = fd4[2], q3 = fd4[3], q4 = fd4[4];
    // stage to LDS once (first 64 threads; all 8 waves share the chunk)
    if (tid < 64) {
        sface[tid * 5 + 0] = q0;
        sface[tid * 5 + 1] = q1;
        sface[tid * 5 + 2] = q2;
        sface[tid * 5 + 3] = q3;
        sface[tid * 5 + 4] = q4;
    }
    __syncthreads();

    const bool valid = (lane < sz) & (q3.x != 0.0f);
    const float s = q3.x > 0.0f ? 1.0f : -1.0f;
    // sign-folded gradients + corner-select bits: fixed per lane, once
    const float g0x = s * q0.x, g0y = s * q0.y;
    const float g1x = s * q1.x, g1y = s * q1.y;
    const float g2x = s * q2.x, g2y = s * q2.y;
    const bool c0y = g0x >= 0.0f, c0x = g0y >= 0.0f;
    const bool c1y = g1x >= 0.0f, c1x = g1y >= 0.0f;
    const bool c2y = g2x >= 0.0f, c2x = g2y >= 0.0f;

    const int dpx = lane & 7, dpy = lane >> 3;

    for (;;) {
        unsigned int j = 0;
        if (lane == 0) j = atomicAdd(&lticket, 1u);
        j = (unsigned int)__shfl((int)j, 0);
        if (j >= 16u) break;
        // chunk-rotated tile order: phase-shifts the 16 chunk-blocks of the
        // same (b, slice) so their zbest writes warm each other's reads
        const unsigned int jj = (j + (unsigned int)ch) & 15u;

        // 4x4 lattice: tile (row,col) strided 4 in each axis
        const int row = (slice >> 2) + 4 * (int)(jj >> 2);
        const int col = (slice & 3) + 4 * (int)(jj & 3);
        const int ix0 = col * 8, iy0 = row * 8;
        const int ix  = ix0 + dpx, iy = iy0 + dpy;
        const float px = 1.0f - (2.0f * (float)ix + 1.0f) / (float)IMG;
        const float py = 1.0f - (2.0f * (float)iy + 1.0f) / (float)IMG;
        const float pxmax = 1.0f - (2.0f * (float)ix0 + 1.0f) / (float)IMG;
        const float pxmin = 1.0f - (2.0f * (float)(ix0 + 7) + 1.0f) / (float)IMG;
        const float pymax = 1.0f - (2.0f * (float)iy0 + 1.0f) / (float)IMG;
        const float pymin = 1.0f - (2.0f * (float)(iy0 + 7) + 1.0f) / (float)IMG;

        const int gp = b * NPIX + iy * IMG + ix;
        // per-lane bound: current zbest z; +INF when no hit yet (sentinel)
        const unsigned ztop = (unsigned)(zbest[gp] >> 32);
        float zbf  = (ztop == 0xFFFFFFFFu) ? INFINITY : __uint_as_float(ztop);
        float zbfp = zbf + ZEPS;   // skip threshold (INF stays INF)

        // conservative half-plane bin test (max over tile rect >= -SLACK)
        bool pass = valid;
        pass &= (g0x * ((c0y ? pymax : pymin) - q0.w)
               - g0y * ((c0x ? pxmin : pxmax) - q0.z)) >= -SLACK;
        pass &= (g1x * ((c1y ? pymax : pymin) - q1.w)
               - g1y * ((c1x ? pxmin : pxmax) - q1.z)) >= -SLACK;
        pass &= (g2x * ((c2y ? pymax : pymin) - q2.w)
               - g2y * ((c2x ? pxmin : pxmax) - q2.z)) >= -SLACK;

        unsigned long long pmin = ~0ULL;
        unsigned long long mask = __ballot(pass);
        while (mask) {
            const int sl = __builtin_ctzll(mask);
            mask &= mask - 1;
            // broadcast face data from LDS (wave-uniform addr -> no conflict)
            const float4 r0 = sface[sl * 5 + 0];
            const float4 r1 = sface[sl * 5 + 1];
            const float4 r2 = sface[sl * 5 + 2];
            const float4 r3 = sface[sl * 5 + 3];   // den, azr, bzr, czr
            const float den = r3.x;
            // exact reference edge functions (shared by filter & exact path)
            float w0 = r0.x * (py - r0.w) - r0.y * (px - r0.z);
            float w1 = r1.x * (py - r1.w) - r1.y * (px - r1.z);
            float w2 = r2.x * (py - r2.w) - r2.y * (px - r2.z);

            // conservative inside: !(w*den < 0) covers w==+-0 and sign-match
            const bool insd = !(w0 * den < 0.0f) & !(w1 * den < 0.0f) &
                              !(w2 * den < 0.0f);
            if (!__any(insd)) continue;

            // cheap z~ via precomputed az*rcp(den) etc. (no rcp in loop)
            const float zt = w0 * r3.y + w1 * r3.z + w2 * r3.w;
            const bool densmall = fabsf(den) < DENSAFE;    // bound invalid
            const bool need = insd & (densmall | ((zt < zbfp) & (zt > -ZEPS)));
            if (__any(need)) {
                // ---- bit-exact reference path ----
                const unsigned ds = __float_as_uint(den) >> 31;
                const bool in0 = (w0 == 0.0f) | ((__float_as_uint(w0) >> 31) == ds);
                const bool in1 = (w1 == 0.0f) | ((__float_as_uint(w1) >> 31) == ds);
                const bool in2 = (w2 == 0.0f) | ((__float_as_uint(w2) >> 31) == ds);
                if (in0 & in1 & in2) {
                    const float4 r4 = sface[sl * 5 + 4];   // az, bz, cz
                    // exact reference rounding for z (3 IEEE divides)
                    float s0 = w0 / den, s1 = w1 / den, s2 = w2 / den;
                    float z  = s0 * r4.x + s1 * r4.y + s2 * r4.z;
                    if (z > 0.0f) {
                        unsigned long long pk =
                            ((unsigned long long)__float_as_uint(z) << 32) |
                            (unsigned)(f0 + sl);
                        pmin = pmin < pk ? pmin : pk;
                        zbf  = fminf(zbf, z);
                        zbfp = zbf + ZEPS;
                    }
                }
            }
        }
        if (pmin != ~0ULL) atomicMin(&zbest[gp], pmin);
    }
}

// Unpack winner; recompute bary + dists from fdata (reference-rounded values).
__global__ __launch_bounds__(256) void pass2(const float* __restrict__ fdata,
                                             const unsigned long long* __restrict__ zbest,
                                             float* __restrict__ out) {
#pragma clang fp contract(off)
    const int gp = blockIdx.x * 256 + threadIdx.x;
    const int b  = gp >> 14;
    const int p  = gp & (NPIX - 1);
    const int ix = p & (IMG - 1), iy = p >> 7;

    unsigned long long packed = zbest[gp];
    float o_face = -1.0f, o_z = -1.0f, o_b0 = -1.0f, o_b1 = -1.0f,
          o_b2 = -1.0f, o_d = -1.0f;

    if (packed != ~0ULL) {
        const int   idx = (int)(unsigned)(packed & 0xffffffffu);
        const float z   = __uint_as_float((unsigned)(packed >> 32));
        const float px  = 1.0f - (2.0f * (float)ix + 1.0f) / (float)IMG;
        const float py  = 1.0f - (2.0f * (float)iy + 1.0f) / (float)IMG;

        const float4* fd4 = (const float4*)(fdata + ((size_t)b * F + idx) * 20);
        float4 q0 = fd4[0], q1 = fd4[1], q2 = fd4[2], q3 = fd4[3], q4 = fd4[4];
        float den = q3.x;
        float w0 = q0.x * (py - q0.w) - q0.y * (px - q0.z);
        float w1 = q1.x * (py - q1.w) - q1.y * (px - q1.z);
        float w2 = q2.x * (py - q2.w) - q2.y * (px - q2.z);
        float s0 = w0 / den, s1 = w1 / den, s2 = w2 / den;
        (void)q4;

        // a=(q2.z,q2.w)  b=(q0.z,q0.w)  c=(q1.z,q1.w): reference-rounded coords
        float d2 = fminf(fminf(seg_dist2(px, py, q2.z, q2.w, q0.z, q0.w),
                               seg_dist2(px, py, q0.z, q0.w, q1.z, q1.w)),
                         seg_dist2(px, py, q1.z, q1.w, q2.z, q2.w));
        o_face = (float)idx; o_z = z;
        o_b0 = s0; o_b1 = s1; o_b2 = s2;
        o_d = -d2;
    }

    out[gp]            = o_face;
    out[B * NPIX + gp] = o_z;
    const int bary_base = 2 * B * NPIX;
    out[bary_base + gp * 3 + 0] = o_b0;
    out[bary_base + gp * 3 + 1] = o_b1;
    out[bary_base + gp * 3 + 2] = o_b2;
    out[5 * B * NPIX + gp] = o_d;
}

} // namespace

extern "C" void kernel_launch(void* const* d_in, const int* in_sizes, int n_in,
                              void* d_out, int out_size, void* d_ws, size_t ws_size,
                              hipStream_t stream) {
    const float* verts = (const float*)d_in[0];  // (B,V,3) f32
    const int*   faces = (const int*)d_in[1];    // (F,3) i32
    float* out = (float*)d_out;

    // ws layout: zbest 512KB | fdata B*F*80 = 320KB
    char* ws = (char*)d_ws;
    unsigned long long* zbest = (unsigned long long*)ws;
    float* fdata = (float*)(ws + (size_t)B * NPIX * 8);

    setup_clear<<<B * NPIX / 256, 256, 0, stream>>>(verts, faces, fdata, zbest);
    // 1024 blocks x 8 waves = 8192 waves, all co-resident (32 waves/CU);
    // block = (chunk, image, lattice-slice), 16 tiles via LDS ticket.
    rast<<<1024, 512, 0, stream>>>(fdata, zbest);
    pass2<<<B * NPIX / 256, 256, 0, stream>>>(fdata, zbest, out);
}